// Round 16
// baseline (549.348 us; speedup 1.0000x reference)
//
#include <hip/hip_runtime.h>

#define T_LEN 2048
#define HID   25
#define LOG2E 1.4426950408889634f

// may_alias vectors for the LDS h-row readback (written as scalar float):
// without may_alias, TBAA licenses hoisting the reads above the publish
// (the R3/R7 corruption).
typedef float vf4 __attribute__((vector_size(16), may_alias));
typedef float vf2 __attribute__((vector_size(8),  may_alias));
typedef float f4  __attribute__((ext_vector_type(4)));
typedef float f2  __attribute__((ext_vector_type(2)));

__device__ __forceinline__ float fast_rcp(float x) { return __builtin_amdgcn_rcpf(x); }
__device__ __forceinline__ float fast_exp2(float x) { return __builtin_amdgcn_exp2f(x); }

// R16 = R15 + three dependency-cycle cuts. At 1 wave/SIMD with a serial
// recurrence, wall (643 cyc/step) = dependency-cycle length, not issue
// (426): the levers are the serial links, not instruction count.
//  1. Gate dots split into TWO pk chains (pairs 0-6 / 7-12), merged by one
//     pk-add + horizontal add: dot dep-chain 13 -> 7 pk.
//  2. Merged reciprocals: sig(i)*tanh(g) = (e_g - 1) * rcp((1+e_i)(1+e_g)),
//     sig(o)*tanh(c) = (e_C - 1) * rcp((1+e_o)(1+e_C)). 10 trans -> 8 and
//     one link shorter per chain.
//  3. Cell state kept pre-scaled: C = 2*log2e*c. The tanh(g) scale folds
//     into fmaf(2L, e_g, -2L), deleting a mul from the serial c->tanh link.
// Everything else identical to R15/R11 (545 us): one chain per 32-lane
// half-wave (lane u owns all 4 gate rows), 1024 waves = 1 wave/SIMD,
// waves_per_eu(1,1), interleaved hbuf broadcast row (slot bijection, junk
// lanes -> dump rows, ZERO conflicts), stride-33 hist for batched y,
// single compile-time fence between publish and readback.
// Weights pre-scaled into the exp2 domain: -log2e (i,f,o), +2log2e (g).

__global__ __attribute__((amdgpu_flat_work_group_size(256, 256),
                          amdgpu_waves_per_eu(1, 1)))
void lstm_fused(
    const float* __restrict__ x,        // [B, T, 1]
    const float* __restrict__ w_ih,     // [100, 1]
    const float* __restrict__ w_hh,     // [100, 25]
    const float* __restrict__ b_ih,     // [100]
    const float* __restrict__ b_hh,     // [100]
    const float* __restrict__ w_dense,  // [1, 25]
    const float* __restrict__ b_dense,  // [1]
    float* __restrict__ out)            // [B, T, 1]
{
    const int tid  = threadIdx.x;
    const int u    = tid & 31;           // hidden unit / y-slot owned by lane
    const int cb   = tid >> 5;           // chain index in block, 0..7
    const int b    = blockIdx.x * 8 + cb;
    const bool act = u < HID;

    // rows 0..7: interleaved h rows per chain; rows 8..15: junk-lane dump.
    __shared__ __align__(16) float hbuf[16][32];
    // y history: 32 steps x 33 floats (stride 33 -> conflict-free y reads).
    __shared__ float hist[8][32][33];

    const float si = -LOG2E, sg = 2.f * LOG2E;

    // ---- recurrent weights as (k, k+12) pairs + (w24, 0), exp2 domain ----
    f2 wI2[13], wF2[13], wG2[13], wO2[13];
#pragma unroll
    for (int m = 0; m < 12; ++m) {
        wI2[m] = act ? f2{si * w_hh[u * HID + m],             si * w_hh[u * HID + m + 12]}             : f2{0.f, 0.f};
        wF2[m] = act ? f2{si * w_hh[(HID + u) * HID + m],     si * w_hh[(HID + u) * HID + m + 12]}     : f2{0.f, 0.f};
        wG2[m] = act ? f2{sg * w_hh[(2 * HID + u) * HID + m], sg * w_hh[(2 * HID + u) * HID + m + 12]} : f2{0.f, 0.f};
        wO2[m] = act ? f2{si * w_hh[(3 * HID + u) * HID + m], si * w_hh[(3 * HID + u) * HID + m + 12]} : f2{0.f, 0.f};
    }
    wI2[12] = act ? f2{si * w_hh[u * HID + 24], 0.f}             : f2{0.f, 0.f};
    wF2[12] = act ? f2{si * w_hh[(HID + u) * HID + 24], 0.f}     : f2{0.f, 0.f};
    wG2[12] = act ? f2{sg * w_hh[(2 * HID + u) * HID + 24], 0.f} : f2{0.f, 0.f};
    wO2[12] = act ? f2{si * w_hh[(3 * HID + u) * HID + 24], 0.f} : f2{0.f, 0.f};

    const float bI  = act ? si * (b_ih[u] + b_hh[u]) : 0.f;
    const float bF  = act ? si * (b_ih[HID + u] + b_hh[HID + u]) : 0.f;
    const float bG  = act ? sg * (b_ih[2 * HID + u] + b_hh[2 * HID + u]) : 0.f;
    const float bO  = act ? si * (b_ih[3 * HID + u] + b_hh[3 * HID + u]) : 0.f;
    const float wxI = act ? si * w_ih[u] : 0.f;
    const float wxF = act ? si * w_ih[HID + u] : 0.f;
    const float wxG = act ? sg * w_ih[2 * HID + u] : 0.f;
    const float wxO = act ? si * w_ih[3 * HID + u] : 0.f;
    const float bd  = b_dense[0];

    // dense weights (wave-uniform loads -> SGPRs)
    float wdv[HID];
#pragma unroll
    for (int i = 0; i < HID; ++i) wdv[i] = w_dense[i];

    // h0 = 0 everywhere (incl. the permanently-zero slot 25 and dump rows)
    hbuf[cb][u] = 0.f;
    hbuf[8 + cb][u] = 0.f;

    // interleaved publish slot (bijection 0..24); junk lanes -> dump row.
    const int slot = (u < 12) ? 2 * u : (u < 24) ? 2 * u - 23 : 24;
    float* hwr = act ? &hbuf[cb][slot] : &hbuf[8 + cb][u];
    const vf4* r4 = (const vf4*)&hbuf[cb][0];
    const vf2* r2 = (const vf2*)&hbuf[cb][24];   // (h24, 0)

    const float4* __restrict__ xp = (const float4*)(x + (size_t)b * T_LEN);
    float* __restrict__ orow = out + (size_t)b * T_LEN;

    // h state kept in the loaded quads; pairs consumed in place.
    f4 hq[6];
#pragma unroll
    for (int m = 0; m < 6; ++m) hq[m] = f4{0.f, 0.f, 0.f, 0.f};
    f2 hq6 = f2{0.f, 0.f};

    float C = 0.f;   // cell state, pre-scaled: C = 2*log2e*c
    const float twoL = 2.f * LOG2E;

    float4 xcur = xp[0];

    for (int it = 0; it < T_LEN / 4; ++it) {
        const int nx = (it + 1 < T_LEN / 4) ? it + 1 : it;
        float4 xnext = xp[nx];  // issued ~4 steps ahead of use
        float xs[4] = {xcur.x, xcur.y, xcur.z, xcur.w};

#pragma unroll
        for (int s = 0; s < 4; ++s) {
            const float xv = xs[s];
            const int t = 4 * it + s;

            // pair p (0..12): p<12 -> hq[p>>1] lo/hi half; p==12 -> hq6.
            // chain0 = pairs 0..6, chain1 = pairs 7..12 (dep chain 13 -> 7).
            f2 hpr[13];
#pragma unroll
            for (int p = 0; p < 12; ++p)
                hpr[p] = (p & 1) ? __builtin_shufflevector(hq[p >> 1], hq[p >> 1], 2, 3)
                                 : __builtin_shufflevector(hq[p >> 1], hq[p >> 1], 0, 1);
            hpr[12] = hq6;

            f2 aI0 = f2{fmaf(xv, wxI, bI), 0.f}, aI1 = f2{0.f, 0.f};
            f2 aF0 = f2{fmaf(xv, wxF, bF), 0.f}, aF1 = f2{0.f, 0.f};
            f2 aG0 = f2{fmaf(xv, wxG, bG), 0.f}, aG1 = f2{0.f, 0.f};
            f2 aO0 = f2{fmaf(xv, wxO, bO), 0.f}, aO1 = f2{0.f, 0.f};
#pragma unroll
            for (int p = 0; p < 7; ++p) {
                aI0 = __builtin_elementwise_fma(hpr[p], wI2[p], aI0);
                aF0 = __builtin_elementwise_fma(hpr[p], wF2[p], aF0);
                aG0 = __builtin_elementwise_fma(hpr[p], wG2[p], aG0);
                aO0 = __builtin_elementwise_fma(hpr[p], wO2[p], aO0);
            }
#pragma unroll
            for (int p = 7; p < 13; ++p) {
                aI1 = __builtin_elementwise_fma(hpr[p], wI2[p], aI1);
                aF1 = __builtin_elementwise_fma(hpr[p], wF2[p], aF1);
                aG1 = __builtin_elementwise_fma(hpr[p], wG2[p], aG1);
                aO1 = __builtin_elementwise_fma(hpr[p], wO2[p], aO1);
            }
            const f2 aIv = aI0 + aI1, aFv = aF0 + aF1;
            const f2 aGv = aG0 + aG1, aOv = aO0 + aO1;
            const float aI = aIv.x + aIv.y;
            const float aF = aFv.x + aFv.y;
            const float aG = aGv.x + aGv.y;
            const float aO = aOv.x + aOv.y;

            // merged-rcp nonlinearities (exp2 domain):
            //   sig(i)*tanh(g)        = (e_g - 1) / ((1+e_i)(1+e_g))
            //   (x2log2e fold: um = 2L*e_g - 2L)
            //   sig(o)*tanh(c)        = (e_C - 1) / ((1+e_o)(1+e_C))
            const float eI = fast_exp2(aI);
            const float eF = fast_exp2(aF);
            const float eG = fast_exp2(aG);
            const float eO = fast_exp2(aO);

            const float sF  = fast_rcp(1.f + eF);               // sig(f)
            const float Rig = fast_rcp((1.f + eI) * (1.f + eG));
            const float um  = fmaf(twoL, eG, -twoL);            // 2L*(e_g-1)
            const float uu  = um * Rig;                         // 2L*sig(i)*tanh(g)

            C = fmaf(sF, C, uu);                                // C = 2L*c
            const float eC  = fast_exp2(C);
            const float Roc = fast_rcp((1.f + eO) * (1.f + eC));
            const float hn  = (eC - 1.f) * Roc;                 // sig(o)*tanh(c)

            // ---- ordered publish -> readback (single compile-time fence;
            // same-wave DS ops execute in order on HW) ----
            *hwr = hn;
            hist[cb][t & 31][u] = hn;
            __asm__ __volatile__("" ::: "memory");
            hq[0] = (f4)r4[0]; hq[1] = (f4)r4[1]; hq[2] = (f4)r4[2];
            hq[3] = (f4)r4[3]; hq[4] = (f4)r4[4]; hq[5] = (f4)r4[5];
            hq6 = (f2)r2[0];                     // (h24, 0)

            // batched y: every 32 steps lane u computes y[t0+u] (full 25-sum,
            // hist reads conflict-free by stride-33), all 32 lanes store.
            if ((t & 31) == 31) {
                const float* hrow = &hist[cb][u][0];   // row for t' = t0 + u
                float ys = 0.f;
#pragma unroll
                for (int i = 0; i < HID; ++i)
                    ys = fmaf(hrow[i], wdv[i], ys);
                orow[(t & ~31) + u] = ys + bd;         // 128 B coalesced
            }
        }
        xcur = xnext;
    }
}

extern "C" void kernel_launch(void* const* d_in, const int* in_sizes, int n_in,
                              void* d_out, int out_size, void* d_ws, size_t ws_size,
                              hipStream_t stream) {
    const float* x       = (const float*)d_in[0];
    const float* w_ih    = (const float*)d_in[1];
    const float* w_hh    = (const float*)d_in[2];
    const float* b_ih    = (const float*)d_in[3];
    const float* b_hh    = (const float*)d_in[4];
    const float* w_dense = (const float*)d_in[5];
    const float* b_dense = (const float*)d_in[6];
    float* out = (float*)d_out;

    // 2048 chains, one per 32-lane half-wave: 256 blocks x 256 threads
    // -> 1024 waves = 1 wave/SIMD chip-wide, 4 waves/CU.
    lstm_fused<<<dim3(256), dim3(256), 0, stream>>>(x, w_ih, w_hh, b_ih, b_hh,
                                                    w_dense, b_dense, out);
}